// Round 1
// baseline (1359.778 us; speedup 1.0000x reference)
//
#include <hip/hip_runtime.h>
#include <stdint.h>

#define S_LEN 2048
#define NB 4
#define NH 8
#define KC_A 4   // k-chunks for sum pass
#define KC_B 2   // k-chunks for pv/write pass

typedef __attribute__((ext_vector_type(8))) short s8v;
typedef __attribute__((ext_vector_type(4))) float f4v;

#define MFMA16(a, b, c) __builtin_amdgcn_mfma_f32_16x16x32_bf16((a), (b), (c), 0, 0, 0)

static __device__ __forceinline__ unsigned short f2bf(float f) {
    unsigned int u = __builtin_bit_cast(unsigned int, f);
    u += 0x7fffu + ((u >> 16) & 1u);
    return (unsigned short)(u >> 16);
}
static __device__ __forceinline__ float bf2f(unsigned short h) {
    unsigned int u = ((unsigned int)h) << 16;
    return __builtin_bit_cast(float, u);
}

// ---- Wt[n][k] = bf16(W[k][n]) : one-time 512x512 transpose+convert ----
__global__ __launch_bounds__(256) void wprep(const float* __restrict__ W,
                                             unsigned short* __restrict__ Wt)
{
    __shared__ float tile[16][17];
    const int tx = threadIdx.x, ty = threadIdx.y;
    const int n0 = blockIdx.x * 16, k0 = blockIdx.y * 16;
    tile[ty][tx] = W[(size_t)(k0 + ty) * 512 + n0 + tx];
    __syncthreads();
    Wt[(size_t)(n0 + ty) * 512 + k0 + tx] = f2bf(tile[tx][ty]);
}

// C[8192][512] = A[8192][512] @ W + bias, with W pre-transposed bf16 Wt[n][k].
// MODE 0: C bf16 row-major. MODE 1: C bf16 transposed per batch: C[b][n][s].
// MODE 2: C fp32 row-major.
// ASRC 0: A fp32 [8192][512]. ASRC 2: A = opart fp32, sum of 2 slices (stride 8192*512).
template <int MODE, int ASRC>
__global__ __launch_bounds__(256) void gemm_tile(
    const void* __restrict__ Av, const unsigned short* __restrict__ Wt,
    const float* __restrict__ bias, void* __restrict__ Cv)
{
    __shared__ unsigned short a_lds[64 * 32];
    __shared__ unsigned short wt_lds[64 * 32];
    const int t = threadIdx.x;
    const int w = t >> 6, lane = t & 63;
    const int quad = lane >> 4, l15 = lane & 15;
    const int m0 = blockIdx.x * 64, n0 = blockIdx.y * 64;

    f4v acc[4] = {};
    const int srow = t >> 2, sc8 = (t & 3) * 8;   // 64 rows x 32 k staging map

    for (int k0 = 0; k0 < 512; k0 += 32) {
        __syncthreads();
        if constexpr (ASRC == 0) {
            const float* ap = (const float*)Av + (size_t)(m0 + srow) * 512 + k0 + sc8;
            f4v v0 = *(const f4v*)ap;
            f4v v1 = *(const f4v*)(ap + 4);
            *(ushort4*)&a_lds[srow * 32 + sc8] =
                make_ushort4(f2bf(v0[0]), f2bf(v0[1]), f2bf(v0[2]), f2bf(v0[3]));
            *(ushort4*)&a_lds[srow * 32 + sc8 + 4] =
                make_ushort4(f2bf(v1[0]), f2bf(v1[1]), f2bf(v1[2]), f2bf(v1[3]));
        } else {
            const float* a0 = (const float*)Av + (size_t)(m0 + srow) * 512 + k0 + sc8;
            const float* a1 = a0 + (size_t)8192 * 512;
            f4v v0 = *(const f4v*)a0 + *(const f4v*)a1;
            f4v v1 = *(const f4v*)(a0 + 4) + *(const f4v*)(a1 + 4);
            *(ushort4*)&a_lds[srow * 32 + sc8] =
                make_ushort4(f2bf(v0[0]), f2bf(v0[1]), f2bf(v0[2]), f2bf(v0[3]));
            *(ushort4*)&a_lds[srow * 32 + sc8 + 4] =
                make_ushort4(f2bf(v1[0]), f2bf(v1[1]), f2bf(v1[2]), f2bf(v1[3]));
        }
        // W staging: straight bf16 copy from pre-transposed Wt (conflict-free)
        *(uint4*)&wt_lds[srow * 32 + sc8] =
            *(const uint4*)(Wt + (size_t)(n0 + srow) * 512 + k0 + sc8);
        __syncthreads();
        s8v wf = *(const s8v*)&wt_lds[(w * 16 + l15) * 32 + quad * 8];
        #pragma unroll
        for (int rt = 0; rt < 4; ++rt) {
            s8v af = *(const s8v*)&a_lds[(rt * 16 + l15) * 32 + quad * 8];
            acc[rt] = MFMA16(af, wf, acc[rt]);
        }
    }

    const float bv = bias[n0 + w * 16 + l15];
    const int n = n0 + w * 16 + l15;
    #pragma unroll
    for (int rt = 0; rt < 4; ++rt) {
        const int mb = m0 + rt * 16 + quad * 4;
        if constexpr (MODE == 0) {
            unsigned short* C = (unsigned short*)Cv;
            #pragma unroll
            for (int r = 0; r < 4; ++r)
                C[(size_t)(mb + r) * 512 + n] = f2bf(acc[rt][r] + bv);
        } else if constexpr (MODE == 1) {
            unsigned short* C = (unsigned short*)Cv;
            ushort4 u = make_ushort4(f2bf(acc[rt][0] + bv), f2bf(acc[rt][1] + bv),
                                     f2bf(acc[rt][2] + bv), f2bf(acc[rt][3] + bv));
            *(ushort4*)&C[(size_t)(mb >> 11) * (512 * 2048) + (size_t)n * 2048 + (mb & 2047)] = u;
        } else {
            float* C = (float*)Cv;
            #pragma unroll
            for (int r = 0; r < 4; ++r)
                C[(size_t)(mb + r) * 512 + n] = acc[rt][r] + bv;
        }
    }
}

// x[8192][32] = qp_bf16[8192][512] @ wx[512][32] + bx
__global__ __launch_bounds__(256) void xproj_kernel(
    const unsigned short* __restrict__ qp, const float* __restrict__ wx,
    const float* __restrict__ bx, float* __restrict__ xout)
{
    __shared__ unsigned short qrow[8 * 512];
    const int t = threadIdx.x;
    const size_t base = (size_t)blockIdx.x * 8 * 512;
    #pragma unroll
    for (int i = 0; i < 2; ++i) {
        const int idx = (i * 256 + t) * 8;
        *(uint4*)&qrow[idx] = *(const uint4*)&qp[base + idx];
    }
    __syncthreads();
    const int r = t >> 5, j = t & 31;
    float acc = bx[j];
    #pragma unroll 8
    for (int d = 0; d < 512; ++d)
        acc = fmaf(bf2f(qrow[r * 512 + d]), wx[d * 32 + j], acc);
    xout[(size_t)blockIdx.x * 256 + t] = acc;
}

// ---- pass A: partial exp-sums over a k-chunk. grid (128, 4, KC_A) ----
__global__ __launch_bounds__(256) void attn_sums(
    const unsigned short* __restrict__ qp, const unsigned short* __restrict__ kp,
    const float* __restrict__ xws, const float* __restrict__ xdiff,
    float* __restrict__ lpart)
{
    __shared__ float x_lds[16 * 32];
    const int t = threadIdx.x, w = t >> 6, lane = t & 63;
    const int quad = lane >> 4, l15 = lane & 15;
    const int b = blockIdx.y, q0 = blockIdx.x * 16, kc = blockIdx.z;
    const int h0 = 2 * w;

    {
        const float* src = xws + ((size_t)(b * S_LEN) + q0) * 32;
        x_lds[t] = src[t];
        x_lds[t + 256] = src[t + 256];
    }
    __syncthreads();

    s8v qf[2][2];
    #pragma unroll
    for (int e = 0; e < 2; ++e)
        #pragma unroll
        for (int kk = 0; kk < 2; ++kk)
            qf[e][kk] = *(const s8v*)&qp[((size_t)(b * S_LEN + q0 + l15)) * 512 +
                                         (h0 + e) * 64 + kk * 32 + quad * 8];
    f4v xh[2][4];
    #pragma unroll
    for (int e = 0; e < 2; ++e)
        #pragma unroll
        for (int r = 0; r < 4; ++r)
            xh[e][r] = *(const f4v*)&x_lds[(quad * 4 + r) * 32 + (h0 + e) * 4];

    const size_t kp_base = (size_t)b * S_LEN * 512;
    const size_t xd_base = ((size_t)(b * S_LEN) + q0) * S_LEN * 4;

    float lp[2][4] = {};
    const int kbeg = kc * (S_LEN / KC_A);
    for (int k0 = kbeg; k0 < kbeg + S_LEN / KC_A; k0 += 32) {
        s8v kf[2][2][2];
        #pragma unroll
        for (int e = 0; e < 2; ++e)
            #pragma unroll
            for (int kt = 0; kt < 2; ++kt)
                #pragma unroll
                for (int kk = 0; kk < 2; ++kk)
                    kf[e][kt][kk] = *(const s8v*)&kp[kp_base +
                        (size_t)(k0 + kt * 16 + l15) * 512 + (h0 + e) * 64 + kk * 32 + quad * 8];
        f4v xd[2][4];
        #pragma unroll
        for (int kt = 0; kt < 2; ++kt)
            #pragma unroll
            for (int r = 0; r < 4; ++r)
                xd[kt][r] = *(const f4v*)&xdiff[xd_base +
                    ((size_t)(quad * 4 + r) * S_LEN + k0 + kt * 16 + l15) * 4];

        #pragma unroll
        for (int e = 0; e < 2; ++e) {
            #pragma unroll
            for (int kt = 0; kt < 2; ++kt) {
                f4v c = {0.f, 0.f, 0.f, 0.f};
                c = MFMA16(qf[e][0], kf[e][kt][0], c);
                c = MFMA16(qf[e][1], kf[e][kt][1], c);
                #pragma unroll
                for (int r = 0; r < 4; ++r) {
                    float bias4 = xd[kt][r][0] * xh[e][r][0] + xd[kt][r][1] * xh[e][r][1] +
                                  xd[kt][r][2] * xh[e][r][2] + xd[kt][r][3] * xh[e][r][3];
                    float lg = c[r] * 0.125f + bias4 * 0.5f;
                    lp[e][r] += __expf(lg);
                }
            }
        }
    }

    #pragma unroll
    for (int e = 0; e < 2; ++e)
        #pragma unroll
        for (int r = 0; r < 4; ++r) {
            float s = lp[e][r];
            s += __shfl_xor(s, 1);
            s += __shfl_xor(s, 2);
            s += __shfl_xor(s, 4);
            s += __shfl_xor(s, 8);
            if (l15 == 0)
                lpart[(((size_t)kc * NB + b) * NH + h0 + e) * S_LEN + q0 + quad * 4 + r] = s;
        }
}

// ---- pass B: recompute chunk, write normalized attn, PV partials. grid (128, 4, KC_B) ----
__global__ __launch_bounds__(256) void attn_pv(
    const unsigned short* __restrict__ qp, const unsigned short* __restrict__ kp,
    const unsigned short* __restrict__ vT, const float* __restrict__ xws,
    const float* __restrict__ xdiff, const float* __restrict__ lpart,
    float* __restrict__ attn, float* __restrict__ opart)
{
    __shared__ float x_lds[16 * 32];
    __shared__ unsigned short p_lds[4 * 2 * 16 * 32];  // [wave][e][q16][k32], wave-private
    const int t = threadIdx.x, w = t >> 6, lane = t & 63;
    const int quad = lane >> 4, l15 = lane & 15;
    const int b = blockIdx.y, q0 = blockIdx.x * 16, kcb = blockIdx.z;
    const int h0 = 2 * w;

    {
        const float* src = xws + ((size_t)(b * S_LEN) + q0) * 32;
        x_lds[t] = src[t];
        x_lds[t + 256] = src[t + 256];
    }
    __syncthreads();

    s8v qf[2][2];
    #pragma unroll
    for (int e = 0; e < 2; ++e)
        #pragma unroll
        for (int kk = 0; kk < 2; ++kk)
            qf[e][kk] = *(const s8v*)&qp[((size_t)(b * S_LEN + q0 + l15)) * 512 +
                                         (h0 + e) * 64 + kk * 32 + quad * 8];
    f4v xh[2][4];
    #pragma unroll
    for (int e = 0; e < 2; ++e)
        #pragma unroll
        for (int r = 0; r < 4; ++r)
            xh[e][r] = *(const f4v*)&x_lds[(quad * 4 + r) * 32 + (h0 + e) * 4];

    const size_t kp_base = (size_t)b * S_LEN * 512;
    const size_t xd_base = ((size_t)(b * S_LEN) + q0) * S_LEN * 4;
    const size_t vt_base = (size_t)b * 512 * S_LEN;

    // rinv from global partial sums (all KC_A chunks)
    float rinv[2][4];
    #pragma unroll
    for (int e = 0; e < 2; ++e)
        #pragma unroll
        for (int r = 0; r < 4; ++r) {
            const int row = q0 + quad * 4 + r;
            float s = 0.f;
            #pragma unroll
            for (int kc = 0; kc < KC_A; ++kc)
                s += lpart[(((size_t)kc * NB + b) * NH + h0 + e) * S_LEN + row];
            rinv[e][r] = 1.0f / s;
        }

    f4v oacc[2][4] = {};
    const int kbeg = kcb * (S_LEN / KC_B);
    for (int k0 = kbeg; k0 < kbeg + S_LEN / KC_B; k0 += 32) {
        s8v kf[2][2][2];
        #pragma unroll
        for (int e = 0; e < 2; ++e)
            #pragma unroll
            for (int kt = 0; kt < 2; ++kt)
                #pragma unroll
                for (int kk = 0; kk < 2; ++kk)
                    kf[e][kt][kk] = *(const s8v*)&kp[kp_base +
                        (size_t)(k0 + kt * 16 + l15) * 512 + (h0 + e) * 64 + kk * 32 + quad * 8];
        f4v xd[2][4];
        #pragma unroll
        for (int kt = 0; kt < 2; ++kt)
            #pragma unroll
            for (int r = 0; r < 4; ++r)
                xd[kt][r] = *(const f4v*)&xdiff[xd_base +
                    ((size_t)(quad * 4 + r) * S_LEN + k0 + kt * 16 + l15) * 4];

        #pragma unroll
        for (int e = 0; e < 2; ++e) {
            #pragma unroll
            for (int kt = 0; kt < 2; ++kt) {
                f4v c = {0.f, 0.f, 0.f, 0.f};
                c = MFMA16(qf[e][0], kf[e][kt][0], c);
                c = MFMA16(qf[e][1], kf[e][kt][1], c);
                #pragma unroll
                for (int r = 0; r < 4; ++r) {
                    float bias4 = xd[kt][r][0] * xh[e][r][0] + xd[kt][r][1] * xh[e][r][1] +
                                  xd[kt][r][2] * xh[e][r][2] + xd[kt][r][3] * xh[e][r][3];
                    float lg = c[r] * 0.125f + bias4 * 0.5f;
                    float P = __expf(lg) * rinv[e][r];
                    size_t aidx = ((size_t)((b * NH + h0 + e) * S_LEN) + q0 + quad * 4 + r) * S_LEN +
                                  k0 + kt * 16 + l15;
                    __builtin_nontemporal_store(P, &attn[aidx]);
                    p_lds[((w * 2 + e) * 16 + quad * 4 + r) * 32 + kt * 16 + l15] = f2bf(P);
                }
            }
            // P (C-layout) -> A-layout via wave-private LDS; in-wave DS ordering
            s8v pa = *(const s8v*)&p_lds[((w * 2 + e) * 16 + l15) * 32 + quad * 8];
            #pragma unroll
            for (int dt = 0; dt < 4; ++dt) {
                s8v vf = *(const s8v*)&vT[vt_base +
                    (size_t)((h0 + e) * 64 + dt * 16 + l15) * S_LEN + k0 + quad * 8];
                oacc[e][dt] = MFMA16(pa, vf, oacc[e][dt]);
            }
        }
    }

    #pragma unroll
    for (int e = 0; e < 2; ++e)
        #pragma unroll
        for (int dt = 0; dt < 4; ++dt)
            #pragma unroll
            for (int r = 0; r < 4; ++r)
                opart[((size_t)kcb * 8192 + b * S_LEN + q0 + quad * 4 + r) * 512 +
                      (h0 + e) * 64 + dt * 16 + l15] = oacc[e][dt][r];
}

extern "C" void kernel_launch(void* const* d_in, const int* in_sizes, int n_in,
                              void* d_out, int out_size, void* d_ws, size_t ws_size,
                              hipStream_t stream) {
    const float* q     = (const float*)d_in[0];
    const float* k     = (const float*)d_in[1];
    const float* v     = (const float*)d_in[2];
    const float* xdiff = (const float*)d_in[3];
    const float* wq    = (const float*)d_in[4];
    const float* bq    = (const float*)d_in[5];
    const float* wk    = (const float*)d_in[6];
    const float* bk    = (const float*)d_in[7];
    const float* wv    = (const float*)d_in[8];
    const float* bv    = (const float*)d_in[9];
    const float* wx    = (const float*)d_in[10];
    const float* bx    = (const float*)d_in[11];
    const float* wo    = (const float*)d_in[12];
    const float* bo    = (const float*)d_in[13];

    float* outp = (float*)d_out;                       // [4,2048,512] fp32
    float* attn = outp + (size_t)NB * S_LEN * 512;     // [4,8,2048,2048] fp32

    const size_t MK = (size_t)8192 * 512;
    const size_t WSZ = (size_t)512 * 512;
    unsigned short* qp   = (unsigned short*)d_ws;      // bf16 [8192][512]
    unsigned short* kpw  = qp + MK;                    // bf16 [8192][512]
    unsigned short* vT   = kpw + MK;                   // bf16 [b][512][2048]
    unsigned short* wtq  = vT + MK;                    // bf16 [512][512] (n-major)
    unsigned short* wtk  = wtq + WSZ;
    unsigned short* wtv  = wtk + WSZ;
    unsigned short* wto  = wtv + WSZ;
    float* xws   = (float*)(wto + WSZ);                // fp32 [8192][32]
    float* lpart = xws + (size_t)8192 * 32;            // fp32 [KC_A][4][8][2048]
    float* opart = lpart + (size_t)KC_A * NB * NH * S_LEN;  // fp32 [KC_B][8192][512]

    dim3 wg(32, 32), wb(16, 16);
    wprep<<<wg, wb, 0, stream>>>(wq, wtq);
    wprep<<<wg, wb, 0, stream>>>(wk, wtk);
    wprep<<<wg, wb, 0, stream>>>(wv, wtv);
    wprep<<<wg, wb, 0, stream>>>(wo, wto);

    dim3 gg(128, 8);
    gemm_tile<0, 0><<<gg, 256, 0, stream>>>(q, wtq, bq, qp);
    gemm_tile<0, 0><<<gg, 256, 0, stream>>>(k, wtk, bk, kpw);
    gemm_tile<1, 0><<<gg, 256, 0, stream>>>(v, wtv, bv, vT);
    xproj_kernel<<<1024, 256, 0, stream>>>(qp, wx, bx, xws);

    attn_sums<<<dim3(128, NB, KC_A), 256, 0, stream>>>(qp, kpw, xws, xdiff, lpart);
    attn_pv<<<dim3(128, NB, KC_B), 256, 0, stream>>>(qp, kpw, vT, xws, xdiff, lpart, attn, opart);

    gemm_tile<2, 2><<<gg, 256, 0, stream>>>(opart, wto, bo, outp);
}

// Round 2
// 1312.863 us; speedup vs baseline: 1.0357x; 1.0357x over previous
//
#include <hip/hip_runtime.h>
#include <stdint.h>

#define S_LEN 2048
#define NB 4
#define NH 8
#define KC_A 4   // k-chunks for sum pass
#define KC_B 2   // k-chunks for pv/write pass

typedef __attribute__((ext_vector_type(8))) short s8v;
typedef __attribute__((ext_vector_type(4))) float f4v;

#define MFMA16(a, b, c) __builtin_amdgcn_mfma_f32_16x16x32_bf16((a), (b), (c), 0, 0, 0)

static __device__ __forceinline__ unsigned short f2bf(float f) {
    unsigned int u = __builtin_bit_cast(unsigned int, f);
    u += 0x7fffu + ((u >> 16) & 1u);
    return (unsigned short)(u >> 16);
}
static __device__ __forceinline__ float bf2f(unsigned short h) {
    unsigned int u = ((unsigned int)h) << 16;
    return __builtin_bit_cast(float, u);
}

// async global->LDS, 16B per lane. ldst must be wave-uniform; gsrc per-lane.
static __device__ __forceinline__ void gload_lds16(const void* gsrc, void* ldst) {
    __builtin_amdgcn_global_load_lds(
        (const __attribute__((address_space(1))) unsigned int*)gsrc,
        (__attribute__((address_space(3))) unsigned int*)ldst, 16, 0, 0);
}

// ---- Wt[n][k] = bf16(W[k][n]) for 4 weights in one launch ----
__global__ __launch_bounds__(256) void wprep4(
    const float* __restrict__ w0, const float* __restrict__ w1,
    const float* __restrict__ w2, const float* __restrict__ w3,
    unsigned short* __restrict__ t0, unsigned short* __restrict__ t1,
    unsigned short* __restrict__ t2, unsigned short* __restrict__ t3)
{
    __shared__ float tile[16][17];
    const float* W;
    unsigned short* Wt;
    switch (blockIdx.z) {
        case 0: W = w0; Wt = t0; break;
        case 1: W = w1; Wt = t1; break;
        case 2: W = w2; Wt = t2; break;
        default: W = w3; Wt = t3; break;
    }
    const int tx = threadIdx.x, ty = threadIdx.y;
    const int n0 = blockIdx.x * 16, k0 = blockIdx.y * 16;
    tile[ty][tx] = W[(size_t)(k0 + ty) * 512 + n0 + tx];
    __syncthreads();
    Wt[(size_t)(n0 + ty) * 512 + k0 + tx] = f2bf(tile[tx][ty]);
}

// C[8192][512] = A[8192][512] @ W + bias, W pre-transposed bf16 Wt[n][k].
// MODE 0: C bf16 row-major. MODE 1: C bf16 transposed per batch: C[b][n][s].
// MODE 2: C fp32 row-major.
// ASRC 0: A fp32. ASRC 2: A = opart fp32, sum of 2 slices (stride 8192*512).
template <int MODE, int ASRC>
static __device__ __forceinline__ void gemm_body(
    const void* __restrict__ Av, const unsigned short* __restrict__ Wt,
    const float* __restrict__ bias, void* __restrict__ Cv)
{
    __shared__ unsigned short a_lds[64 * 32];
    __shared__ unsigned short wt_lds[64 * 32];
    const int t = threadIdx.x;
    const int w = t >> 6, lane = t & 63;
    const int quad = lane >> 4, l15 = lane & 15;
    const int m0 = blockIdx.x * 64, n0 = blockIdx.y * 64;

    f4v acc[4] = {};
    const int srow = t >> 2, sc8 = (t & 3) * 8;

    for (int k0 = 0; k0 < 512; k0 += 32) {
        __syncthreads();
        if constexpr (ASRC == 0) {
            const float* ap = (const float*)Av + (size_t)(m0 + srow) * 512 + k0 + sc8;
            f4v v0 = *(const f4v*)ap;
            f4v v1 = *(const f4v*)(ap + 4);
            *(ushort4*)&a_lds[srow * 32 + sc8] =
                make_ushort4(f2bf(v0[0]), f2bf(v0[1]), f2bf(v0[2]), f2bf(v0[3]));
            *(ushort4*)&a_lds[srow * 32 + sc8 + 4] =
                make_ushort4(f2bf(v1[0]), f2bf(v1[1]), f2bf(v1[2]), f2bf(v1[3]));
        } else {
            const float* a0 = (const float*)Av + (size_t)(m0 + srow) * 512 + k0 + sc8;
            const float* a1 = a0 + (size_t)8192 * 512;
            f4v v0 = *(const f4v*)a0 + *(const f4v*)a1;
            f4v v1 = *(const f4v*)(a0 + 4) + *(const f4v*)(a1 + 4);
            *(ushort4*)&a_lds[srow * 32 + sc8] =
                make_ushort4(f2bf(v0[0]), f2bf(v0[1]), f2bf(v0[2]), f2bf(v0[3]));
            *(ushort4*)&a_lds[srow * 32 + sc8 + 4] =
                make_ushort4(f2bf(v1[0]), f2bf(v1[1]), f2bf(v1[2]), f2bf(v1[3]));
        }
        *(uint4*)&wt_lds[srow * 32 + sc8] =
            *(const uint4*)(Wt + (size_t)(n0 + srow) * 512 + k0 + sc8);
        __syncthreads();
        s8v wf = *(const s8v*)&wt_lds[(w * 16 + l15) * 32 + quad * 8];
        #pragma unroll
        for (int rt = 0; rt < 4; ++rt) {
            s8v af = *(const s8v*)&a_lds[(rt * 16 + l15) * 32 + quad * 8];
            acc[rt] = MFMA16(af, wf, acc[rt]);
        }
    }

    const float bv = bias[n0 + w * 16 + l15];
    const int n = n0 + w * 16 + l15;
    #pragma unroll
    for (int rt = 0; rt < 4; ++rt) {
        const int mb = m0 + rt * 16 + quad * 4;
        if constexpr (MODE == 0) {
            unsigned short* C = (unsigned short*)Cv;
            #pragma unroll
            for (int r = 0; r < 4; ++r)
                C[(size_t)(mb + r) * 512 + n] = f2bf(acc[rt][r] + bv);
        } else if constexpr (MODE == 1) {
            unsigned short* C = (unsigned short*)Cv;
            ushort4 u = make_ushort4(f2bf(acc[rt][0] + bv), f2bf(acc[rt][1] + bv),
                                     f2bf(acc[rt][2] + bv), f2bf(acc[rt][3] + bv));
            *(ushort4*)&C[(size_t)(mb >> 11) * (512 * 2048) + (size_t)n * 2048 + (mb & 2047)] = u;
        } else {
            float* C = (float*)Cv;
            #pragma unroll
            for (int r = 0; r < 4; ++r)
                C[(size_t)(mb + r) * 512 + n] = acc[rt][r] + bv;
        }
    }
}

// all three projection GEMMs in one launch (z = 0:q, 1:k, 2:v-transposed)
__global__ __launch_bounds__(256) void gemm3(
    const float* __restrict__ q, const float* __restrict__ k, const float* __restrict__ v,
    const unsigned short* __restrict__ wtq, const unsigned short* __restrict__ wtk,
    const unsigned short* __restrict__ wtv,
    const float* __restrict__ bq, const float* __restrict__ bk, const float* __restrict__ bv,
    unsigned short* __restrict__ qp, unsigned short* __restrict__ kpw,
    unsigned short* __restrict__ vT)
{
    if (blockIdx.z == 0) gemm_body<0, 0>(q, wtq, bq, qp);
    else if (blockIdx.z == 1) gemm_body<0, 0>(k, wtk, bk, kpw);
    else gemm_body<1, 0>(v, wtv, bv, vT);
}

__global__ __launch_bounds__(256) void gemm_final(
    const float* __restrict__ opart, const unsigned short* __restrict__ wto,
    const float* __restrict__ bo, float* __restrict__ outp)
{
    gemm_body<2, 2>(opart, wto, bo, outp);
}

// x[8192][32] = qp_bf16[8192][512] @ wx[512][32] + bx
__global__ __launch_bounds__(256) void xproj_kernel(
    const unsigned short* __restrict__ qp, const float* __restrict__ wx,
    const float* __restrict__ bx, float* __restrict__ xout)
{
    __shared__ unsigned short qrow[8 * 512];
    const int t = threadIdx.x;
    const size_t base = (size_t)blockIdx.x * 8 * 512;
    #pragma unroll
    for (int i = 0; i < 2; ++i) {
        const int idx = (i * 256 + t) * 8;
        *(uint4*)&qrow[idx] = *(const uint4*)&qp[base + idx];
    }
    __syncthreads();
    const int r = t >> 5, j = t & 31;
    float acc = bx[j];
    #pragma unroll 8
    for (int d = 0; d < 512; ++d)
        acc = fmaf(bf2f(qrow[r * 512 + d]), wx[d * 32 + j], acc);
    xout[(size_t)blockIdx.x * 256 + t] = acc;
}

// ---- pass A: partial exp-sums. 8 waves/block, 1 head/wave, xdiff dbuf in LDS ----
__global__ __launch_bounds__(512, 4) void attn_sums(
    const unsigned short* __restrict__ qp, const unsigned short* __restrict__ kp,
    const float* __restrict__ xws, const float* __restrict__ xdiff,
    float* __restrict__ lpart)
{
    __shared__ float xtile[2][16 * 64 * 4];  // 2 x 16KB: [buf][q16][k64][f4]
    const int t = threadIdx.x, w = t >> 6, lane = t & 63;
    const int quad = lane >> 4, l15 = lane & 15;
    const int b = blockIdx.y, q0 = blockIdx.x * 16, kc = blockIdx.z;
    const int h = w;

    s8v qf[2];
    #pragma unroll
    for (int kk = 0; kk < 2; ++kk)
        qf[kk] = *(const s8v*)&qp[((size_t)(b * S_LEN + q0 + l15)) * 512 +
                                  h * 64 + kk * 32 + quad * 8];
    f4v xh[4];
    #pragma unroll
    for (int r = 0; r < 4; ++r)
        xh[r] = *(const f4v*)&xws[((size_t)(b * S_LEN + q0 + quad * 4 + r)) * 32 + h * 4];

    const size_t kp_base = (size_t)b * S_LEN * 512;
    const size_t xd_base = ((size_t)(b * S_LEN + q0)) * S_LEN * 4;  // float index

    float lp[4] = {};
    const int kbeg = kc * (S_LEN / KC_A);
    const int nt = (S_LEN / KC_A) / 64;

    // prologue stage tile 0
    #pragma unroll
    for (int j = 0; j < 2; ++j)
        gload_lds16(xdiff + xd_base + (size_t)(w * 2 + j) * (S_LEN * 4) + (size_t)(kbeg + lane) * 4,
                    &xtile[0][(w * 2 + j) * 256]);

    for (int tix = 0; tix < nt; ++tix) {
        __syncthreads();  // drains vmcnt: buf[tix&1] staged, prev reads done
        const int k0 = kbeg + tix * 64;
        if (tix + 1 < nt) {
            #pragma unroll
            for (int j = 0; j < 2; ++j)
                gload_lds16(xdiff + xd_base + (size_t)(w * 2 + j) * (S_LEN * 4) +
                                (size_t)(k0 + 64 + lane) * 4,
                            &xtile[(tix + 1) & 1][(w * 2 + j) * 256]);
        }
        const float* xt = xtile[tix & 1];

        #pragma unroll
        for (int ks = 0; ks < 2; ++ks) {
            const int kk0 = k0 + ks * 32;
            s8v kf[2][2];
            #pragma unroll
            for (int kt = 0; kt < 2; ++kt)
                #pragma unroll
                for (int kk = 0; kk < 2; ++kk)
                    kf[kt][kk] = *(const s8v*)&kp[kp_base +
                        (size_t)(kk0 + kt * 16 + l15) * 512 + h * 64 + kk * 32 + quad * 8];
            #pragma unroll
            for (int kt = 0; kt < 2; ++kt) {
                f4v c = {0.f, 0.f, 0.f, 0.f};
                c = MFMA16(qf[0], kf[kt][0], c);
                c = MFMA16(qf[1], kf[kt][1], c);
                #pragma unroll
                for (int r = 0; r < 4; ++r) {
                    f4v xd = *(const f4v*)&xt[((quad * 4 + r) * 64 + ks * 32 + kt * 16 + l15) * 4];
                    float bias4 = xd[0] * xh[r][0] + xd[1] * xh[r][1] +
                                  xd[2] * xh[r][2] + xd[3] * xh[r][3];
                    lp[r] += __expf(c[r] * 0.125f + bias4 * 0.5f);
                }
            }
        }
    }

    #pragma unroll
    for (int r = 0; r < 4; ++r) {
        float s = lp[r];
        s += __shfl_xor(s, 1);
        s += __shfl_xor(s, 2);
        s += __shfl_xor(s, 4);
        s += __shfl_xor(s, 8);
        if (l15 == 0)
            lpart[(((size_t)kc * NB + b) * NH + h) * S_LEN + q0 + quad * 4 + r] = s;
    }
}

// ---- pass B: recompute, write normalized attn, PV partials ----
__global__ __launch_bounds__(512, 4) void attn_pv(
    const unsigned short* __restrict__ qp, const unsigned short* __restrict__ kp,
    const unsigned short* __restrict__ vT, const float* __restrict__ xws,
    const float* __restrict__ xdiff, const float* __restrict__ lpart,
    float* __restrict__ attn, float* __restrict__ opart)
{
    __shared__ float xtile[2][16 * 64 * 4];          // 32KB
    __shared__ unsigned short p_lds[8 * 16 * 32];    // 8KB, wave-private slices
    const int t = threadIdx.x, w = t >> 6, lane = t & 63;
    const int quad = lane >> 4, l15 = lane & 15;
    const int b = blockIdx.y, q0 = blockIdx.x * 16, kcb = blockIdx.z;
    const int h = w;

    s8v qf[2];
    #pragma unroll
    for (int kk = 0; kk < 2; ++kk)
        qf[kk] = *(const s8v*)&qp[((size_t)(b * S_LEN + q0 + l15)) * 512 +
                                  h * 64 + kk * 32 + quad * 8];
    f4v xh[4];
    #pragma unroll
    for (int r = 0; r < 4; ++r)
        xh[r] = *(const f4v*)&xws[((size_t)(b * S_LEN + q0 + quad * 4 + r)) * 32 + h * 4];

    float rinv[4];
    #pragma unroll
    for (int r = 0; r < 4; ++r) {
        const int row = q0 + quad * 4 + r;
        float s = 0.f;
        #pragma unroll
        for (int kc = 0; kc < KC_A; ++kc)
            s += lpart[(((size_t)kc * NB + b) * NH + h) * S_LEN + row];
        rinv[r] = 1.0f / s;
    }

    const size_t kp_base = (size_t)b * S_LEN * 512;
    const size_t xd_base = ((size_t)(b * S_LEN + q0)) * S_LEN * 4;
    const size_t vt_base = (size_t)b * 512 * S_LEN;
    const size_t attn_row = ((size_t)((b * NH + h) * S_LEN) + q0) * S_LEN;

    f4v oacc[4] = {};
    const int kbeg = kcb * (S_LEN / KC_B);
    const int nt = (S_LEN / KC_B) / 64;

    #pragma unroll
    for (int j = 0; j < 2; ++j)
        gload_lds16(xdiff + xd_base + (size_t)(w * 2 + j) * (S_LEN * 4) + (size_t)(kbeg + lane) * 4,
                    &xtile[0][(w * 2 + j) * 256]);

    for (int tix = 0; tix < nt; ++tix) {
        __syncthreads();
        const int k0 = kbeg + tix * 64;
        if (tix + 1 < nt) {
            #pragma unroll
            for (int j = 0; j < 2; ++j)
                gload_lds16(xdiff + xd_base + (size_t)(w * 2 + j) * (S_LEN * 4) +
                                (size_t)(k0 + 64 + lane) * 4,
                            &xtile[(tix + 1) & 1][(w * 2 + j) * 256]);
        }
        const float* xt = xtile[tix & 1];

        #pragma unroll
        for (int ks = 0; ks < 2; ++ks) {
            const int kk0 = k0 + ks * 32;
            s8v kf[2][2];
            #pragma unroll
            for (int kt = 0; kt < 2; ++kt)
                #pragma unroll
                for (int kk = 0; kk < 2; ++kk)
                    kf[kt][kk] = *(const s8v*)&kp[kp_base +
                        (size_t)(kk0 + kt * 16 + l15) * 512 + h * 64 + kk * 32 + quad * 8];
            #pragma unroll
            for (int kt = 0; kt < 2; ++kt) {
                f4v c = {0.f, 0.f, 0.f, 0.f};
                c = MFMA16(qf[0], kf[kt][0], c);
                c = MFMA16(qf[1], kf[kt][1], c);
                #pragma unroll
                for (int r = 0; r < 4; ++r) {
                    f4v xd = *(const f4v*)&xt[((quad * 4 + r) * 64 + ks * 32 + kt * 16 + l15) * 4];
                    float bias4 = xd[0] * xh[r][0] + xd[1] * xh[r][1] +
                                  xd[2] * xh[r][2] + xd[3] * xh[r][3];
                    float P = __expf(c[r] * 0.125f + bias4 * 0.5f) * rinv[r];
                    __builtin_nontemporal_store(P,
                        &attn[attn_row + (size_t)(quad * 4 + r) * S_LEN + kk0 + kt * 16 + l15]);
                    p_lds[(h * 16 + quad * 4 + r) * 32 + kt * 16 + l15] = f2bf(P);
                }
            }
            // P (C-layout) -> A-layout via wave-private LDS; in-wave DS ordering
            s8v pa = *(const s8v*)&p_lds[(h * 16 + l15) * 32 + quad * 8];
            #pragma unroll
            for (int dt = 0; dt < 4; ++dt) {
                s8v vf = *(const s8v*)&vT[vt_base +
                    (size_t)(h * 64 + dt * 16 + l15) * S_LEN + kk0 + quad * 8];
                oacc[dt] = MFMA16(pa, vf, oacc[dt]);
            }
        }
    }

    #pragma unroll
    for (int dt = 0; dt < 4; ++dt)
        #pragma unroll
        for (int r = 0; r < 4; ++r)
            opart[((size_t)kcb * 8192 + b * S_LEN + q0 + quad * 4 + r) * 512 +
                  h * 64 + dt * 16 + l15] = oacc[dt][r];
}

extern "C" void kernel_launch(void* const* d_in, const int* in_sizes, int n_in,
                              void* d_out, int out_size, void* d_ws, size_t ws_size,
                              hipStream_t stream) {
    const float* q     = (const float*)d_in[0];
    const float* k     = (const float*)d_in[1];
    const float* v     = (const float*)d_in[2];
    const float* xdiff = (const float*)d_in[3];
    const float* wq    = (const float*)d_in[4];
    const float* bq    = (const float*)d_in[5];
    const float* wk    = (const float*)d_in[6];
    const float* bk    = (const float*)d_in[7];
    const float* wv    = (const float*)d_in[8];
    const float* bv    = (const float*)d_in[9];
    const float* wx    = (const float*)d_in[10];
    const float* bx    = (const float*)d_in[11];
    const float* wo    = (const float*)d_in[12];
    const float* bo    = (const float*)d_in[13];

    float* outp = (float*)d_out;                       // [4,2048,512] fp32
    float* attn = outp + (size_t)NB * S_LEN * 512;     // [4,8,2048,2048] fp32

    const size_t MK = (size_t)8192 * 512;
    const size_t WSZ = (size_t)512 * 512;
    unsigned short* qp   = (unsigned short*)d_ws;      // bf16 [8192][512]
    unsigned short* kpw  = qp + MK;                    // bf16 [8192][512]
    unsigned short* vT   = kpw + MK;                   // bf16 [b][512][2048]
    unsigned short* wtq  = vT + MK;                    // bf16 [512][512] (n-major)
    unsigned short* wtk  = wtq + WSZ;
    unsigned short* wtv  = wtk + WSZ;
    unsigned short* wto  = wtv + WSZ;
    float* xws   = (float*)(wto + WSZ);                // fp32 [8192][32]
    float* lpart = xws + (size_t)8192 * 32;            // fp32 [KC_A][4][8][2048]
    float* opart = lpart + (size_t)KC_A * NB * NH * S_LEN;  // fp32 [KC_B][8192][512]

    wprep4<<<dim3(32, 32, 4), dim3(16, 16), 0, stream>>>(wq, wk, wv, wo, wtq, wtk, wtv, wto);
    gemm3<<<dim3(128, 8, 3), 256, 0, stream>>>(q, k, v, wtq, wtk, wtv, bq, bk, bv, qp, kpw, vT);
    xproj_kernel<<<1024, 256, 0, stream>>>(qp, wx, bx, xws);

    attn_sums<<<dim3(128, NB, KC_A), 512, 0, stream>>>(qp, kpw, xws, xdiff, lpart);
    attn_pv<<<dim3(128, NB, KC_B), 512, 0, stream>>>(qp, kpw, vT, xws, xdiff, lpart, attn, opart);

    gemm_final<<<dim3(128, 8), 256, 0, stream>>>(opart, wto, bo, outp);
}